// Round 1
// baseline (339.815 us; speedup 1.0000x reference)
//
#include <hip/hip_runtime.h>
#include <cstdint>
#include <cstddef>

#define IN_F 8192
#define OUT_F 8192
#define BATCH 512
#define KSPLIT 4
#define KSLICE (IN_F / KSPLIT) /* 2048 */
#define BK 32
#define NIT (KSLICE / BK) /* 64 */
#define BM 128
#define BN 256

typedef __bf16 bf16x8 __attribute__((ext_vector_type(8)));
typedef float floatx4 __attribute__((ext_vector_type(4)));

// fp32 -> bf16 round-to-nearest-even
__device__ __forceinline__ ushort f2bf(float f) {
  uint32_t u = __float_as_uint(f);
  u += 0x7FFFu + ((u >> 16) & 1u);
  return (ushort)(u >> 16);
}

// one low byte (2 nibbles) of a packed int -> bf16x2 of biased weights (q+136):
// low half = 0x4300|hi_nibble (even k), high half = 0x4300|lo_nibble (odd k)
__device__ __forceinline__ uint32_t dq(int p) {
  uint32_t u = (uint32_t)p;
  return (((u >> 4) & 0xFu) | ((u & 0xFu) << 16)) | 0x43004300u;
}

// async global->LDS, 16B per lane, LDS dest = wave-uniform base + lane*16
__device__ __forceinline__ void gl16(const void* g, uint32_t* l) {
  __builtin_amdgcn_global_load_lds(
      (const __attribute__((address_space(1))) uint32_t*)g,
      (__attribute__((address_space(3))) uint32_t*)l, 16, 0, 0);
}

// Pass 1: x fp32 -> bf16, plus PER-SLICE rowsums of the converted values.
__global__ __launch_bounds__(256) void cvt_rowsum(const float* __restrict__ x,
                                                  ushort* __restrict__ xb,
                                                  float* __restrict__ rowsum) {
  const int b = blockIdx.x;
  const int t = threadIdx.x;
  const float4* xr = (const float4*)(x + (size_t)b * IN_F);
  ushort4* xo = (ushort4*)(xb + (size_t)b * IN_F);
  float s[4] = {0.f, 0.f, 0.f, 0.f};
#pragma unroll
  for (int i = 0; i < 8; ++i) {
    float4 v = xr[i * 256 + t];
    ushort4 o;
    o.x = f2bf(v.x); o.y = f2bf(v.y); o.z = f2bf(v.z); o.w = f2bf(v.w);
    xo[i * 256 + t] = o;
    s[i >> 1] += __uint_as_float((uint32_t)o.x << 16) + __uint_as_float((uint32_t)o.y << 16)
               + __uint_as_float((uint32_t)o.z << 16) + __uint_as_float((uint32_t)o.w << 16);
  }
  __shared__ float red[4][4];
  const int lane = t & 63, wid = t >> 6;
#pragma unroll
  for (int j = 0; j < 4; ++j) {
    float v = s[j];
#pragma unroll
    for (int off = 32; off >= 1; off >>= 1) v += __shfl_down(v, off, 64);
    if (lane == 0) red[wid][j] = v;
  }
  __syncthreads();
  if (t < 4) rowsum[t * BATCH + b] = red[0][t] + red[1][t] + red[2][t] + red[3][t];
}

// Split-K quantized GEMM. Block: 128(m) x 256(n) x KSLICE(k).
// 4 waves (2m x 2n), each wave owns a 64x128 output tile -> 42.7 FLOP per
// LDS byte read (vs 32 before), so LDS BW no longer caps MFMA.
// LDS layout: [row][chunk] of 16B chunks, swizzled chunk' = chunk ^ ((row>>1)&3)
// -> every b128 read/write instruction spreads over all 32 banks.
// A staged by global_load_lds (linear dest, INVERSE-swizzled global source);
// B staged through regs (nibble unpack) with swizzled ds_write_b128.
__global__ __launch_bounds__(256, 2) void qgemm(const ushort* __restrict__ xb,
                                                const int* __restrict__ pw,
                                                const float* __restrict__ scale,
                                                const float* __restrict__ rowsum,
                                                float* __restrict__ out) {
  __shared__ uint32_t As[2 * BM * 16];  // 2 bufs x 128 rows x 32 bf16, 16 KB
  __shared__ uint32_t Bs[2 * BN * 16];  // 2 bufs x 256 rows x 32 bf16, 32 KB

  const int tid = threadIdx.x;
  const int lane = tid & 63;
  const int w = tid >> 6;
  const int wm = w & 1, wn = w >> 1;
  const int lr = lane & 15, lq = lane >> 4;

  const int n0 = blockIdx.x * BN;
  const int m0 = blockIdx.y * BM;
  const int ks = blockIdx.z;

  // ---- A staging via global_load_lds ----
  // wave w, instr j: lanes write LDS linearly -> row w*32+j*16+(l>>2), slot l&3.
  // Slot p of row r must hold logical chunk q = p ^ ((r>>1)&3); with row base
  // a multiple of 16 the key reduces to (l>>3)&3, folded into the global addr.
  const int qsw = (lane & 3) ^ ((lane >> 3) & 3);
  const char* aG = (const char*)xb
      + (size_t)(m0 + w * 32 + (lane >> 2)) * (IN_F * 2)
      + (size_t)ks * (KSLICE * 2) + qsw * 16;
  uint32_t* aL = As + (w * 32) * 16;  // wave-uniform; +256 words = +16 rows

  // ---- B staging: thread t stages full row n0+t (32 weights = 16 ints) ----
  const int4* bG = (const int4*)(pw + (size_t)(n0 + tid) * (IN_F / 2) + ks * (KSLICE / 2));
  uint32_t* bW = Bs + tid * 16;
  const int bkey = (tid >> 1) & 3;

  // ---- swizzled fragment read pointers ----
  // row = tilebase + i*16 + lr with tilebase,i*16 multiples of 8 -> key = (lr>>1)&3
  const int rkey = (lr >> 1) & 3;
  const uint32_t* aR = As + (wm * 64 + lr) * 16 + (lq ^ rkey) * 4;
  const uint32_t* bR = Bs + (wn * 128 + lr) * 16 + (lq ^ rkey) * 4;

  floatx4 acc[4][8] = {};

  // prologue: A tile 0 -> LDS buf0 (async), B tile 0 -> regs
  gl16(aG, aL);
  gl16(aG + (size_t)16 * (IN_F * 2), aL + 256);
  int4 pb0 = bG[0], pb1 = bG[1], pb2 = bG[2], pb3 = bG[3];

  for (int it = 0; it < NIT; ++it) {
    const int offA = (it & 1) * (BM * 16);
    const int offB = (it & 1) * (BN * 16);
    // unpack + swizzled-write B tile(it)
    int4 u0, u1, u2, u3;
    u0.x = dq(pb0.x); u0.y = dq(pb0.y); u0.z = dq(pb0.z); u0.w = dq(pb0.w);
    u1.x = dq(pb1.x); u1.y = dq(pb1.y); u1.z = dq(pb1.z); u1.w = dq(pb1.w);
    u2.x = dq(pb2.x); u2.y = dq(pb2.y); u2.z = dq(pb2.z); u2.w = dq(pb2.w);
    u3.x = dq(pb3.x); u3.y = dq(pb3.y); u3.z = dq(pb3.z); u3.w = dq(pb3.w);
    *(int4*)(bW + offB + ((0 ^ bkey) << 2)) = u0;
    *(int4*)(bW + offB + ((1 ^ bkey) << 2)) = u1;
    *(int4*)(bW + offB + ((2 ^ bkey) << 2)) = u2;
    *(int4*)(bW + offB + ((3 ^ bkey) << 2)) = u3;
    __syncthreads();  // compiler drains vmcnt (A gload) + lgkmcnt (B writes)
    // prefetch tile(it+1): A async into other LDS buf, B into regs;
    // a full compute phase to land before they're needed.
    if (it + 1 < NIT) {
      const int offA2 = ((it + 1) & 1) * (BM * 16);
      const char* aN = aG + (size_t)(it + 1) * 64;
      gl16(aN, aL + offA2);
      gl16(aN + (size_t)16 * (IN_F * 2), aL + offA2 + 256);
      pb0 = bG[(it + 1) * 4 + 0]; pb1 = bG[(it + 1) * 4 + 1];
      pb2 = bG[(it + 1) * 4 + 2]; pb3 = bG[(it + 1) * 4 + 3];
    }
    // compute tile(it)
    bf16x8 av[4], bv[8];
#pragma unroll
    for (int i = 0; i < 4; ++i) av[i] = *(const bf16x8*)(aR + offA + i * 256);
#pragma unroll
    for (int i = 0; i < 8; ++i) bv[i] = *(const bf16x8*)(bR + offB + i * 256);
#pragma unroll
    for (int mi = 0; mi < 4; ++mi)
#pragma unroll
      for (int ni = 0; ni < 8; ++ni)
        acc[mi][ni] = __builtin_amdgcn_mfma_f32_16x16x32_bf16(av[mi], bv[ni],
                                                              acc[mi][ni], 0, 0, 0);
  }

  // epilogue: C/D layout col=lane&15, row=(lane>>4)*4+reg
  const int om = m0 + wm * 64 + lq * 4;
  const int on = n0 + wn * 128 + lr;
  float scv[8];
#pragma unroll
  for (int ni = 0; ni < 8; ++ni) scv[ni] = scale[on + ni * 16];
  float rsv[4][4];
#pragma unroll
  for (int mi = 0; mi < 4; ++mi)
#pragma unroll
    for (int rr = 0; rr < 4; ++rr)
      rsv[mi][rr] = rowsum[ks * BATCH + om + mi * 16 + rr];

#pragma unroll
  for (int mi = 0; mi < 4; ++mi)
#pragma unroll
    for (int ni = 0; ni < 8; ++ni) {
      const float s = scv[ni];
      float* op = out + (size_t)(om + mi * 16) * OUT_F + (on + ni * 16);
#pragma unroll
      for (int rr = 0; rr < 4; ++rr)
        atomicAdd(op + (size_t)rr * OUT_F, s * (acc[mi][ni][rr] - 136.f * rsv[mi][rr]));
    }
}

extern "C" void kernel_launch(void* const* d_in, const int* in_sizes, int n_in,
                              void* d_out, int out_size, void* d_ws, size_t ws_size,
                              hipStream_t stream) {
  const float* x = (const float*)d_in[0];
  const int* pw = (const int*)d_in[1];
  const float* scale = (const float*)d_in[2];
  float* out = (float*)d_out;

  ushort* xb = (ushort*)d_ws;  // 8 MiB
  float* rowsum = (float*)((char*)d_ws + (size_t)BATCH * IN_F * sizeof(ushort));  // 4x512 f32

  cvt_rowsum<<<BATCH, 256, 0, stream>>>(x, xb, rowsum);
  hipMemsetAsync(out, 0, (size_t)out_size * sizeof(float), stream);
  dim3 grid(OUT_F / BN, BATCH / BM, KSPLIT);
  qgemm<<<grid, 256, 0, stream>>>(xb, pw, scale, rowsum, out);
}

// Round 2
// 308.390 us; speedup vs baseline: 1.1019x; 1.1019x over previous
//
#include <hip/hip_runtime.h>
#include <cstdint>
#include <cstddef>

#define IN_F 8192
#define OUT_F 8192
#define BATCH 512
#define KSPLIT 4
#define KSLICE (IN_F / KSPLIT) /* 2048 */
#define BK 32
#define NIT (KSLICE / BK) /* 64 */
#define BM 128
#define BN 128

typedef __bf16 bf16x8 __attribute__((ext_vector_type(8)));
typedef float floatx4 __attribute__((ext_vector_type(4)));

// fp32 -> bf16 round-to-nearest-even
__device__ __forceinline__ ushort f2bf(float f) {
  uint32_t u = __float_as_uint(f);
  u += 0x7FFFu + ((u >> 16) & 1u);
  return (ushort)(u >> 16);
}

// one low byte (2 nibbles) of a packed int -> bf16x2 of biased weights (q+136):
// low half = 0x4300|hi_nibble (even k), high half = 0x4300|lo_nibble (odd k)
// (0x4300 = 128.0f bf16; OR-ing nibble into mantissa low bits gives 128+nib)
__device__ __forceinline__ uint32_t dq(int p) {
  uint32_t u = (uint32_t)p;
  return (((u >> 4) & 0xFu) | ((u & 0xFu) << 16)) | 0x43004300u;
}

// async global->LDS, 16B per lane, LDS dest = wave-uniform base + lane*16
__device__ __forceinline__ void gl16(const void* g, uint32_t* l) {
  __builtin_amdgcn_global_load_lds(
      (const __attribute__((address_space(1))) uint32_t*)g,
      (__attribute__((address_space(3))) uint32_t*)l, 16, 0, 0);
}

// Pass 1: x fp32 -> bf16, per-slice rowsums of converted values, and zero the
// output (folded here so the memset dispatch disappears from the serial chain).
__global__ __launch_bounds__(256) void cvt_rowsum(const float* __restrict__ x,
                                                  ushort* __restrict__ xb,
                                                  float* __restrict__ rowsum,
                                                  float* __restrict__ out) {
  const int b = blockIdx.x;
  const int t = threadIdx.x;
  const float4* xr = (const float4*)(x + (size_t)b * IN_F);
  ushort4* xo = (ushort4*)(xb + (size_t)b * IN_F);
  float4 z = {0.f, 0.f, 0.f, 0.f};
  float4* orow = (float4*)(out + (size_t)b * OUT_F);
  float s[4] = {0.f, 0.f, 0.f, 0.f};
#pragma unroll
  for (int i = 0; i < 8; ++i) {
    float4 v = xr[i * 256 + t];
    ushort4 o;
    o.x = f2bf(v.x); o.y = f2bf(v.y); o.z = f2bf(v.z); o.w = f2bf(v.w);
    xo[i * 256 + t] = o;
    orow[i * 256 + t] = z;
    s[i >> 1] += __uint_as_float((uint32_t)o.x << 16) + __uint_as_float((uint32_t)o.y << 16)
               + __uint_as_float((uint32_t)o.z << 16) + __uint_as_float((uint32_t)o.w << 16);
  }
  __shared__ float red[4][4];
  const int lane = t & 63, wid = t >> 6;
#pragma unroll
  for (int j = 0; j < 4; ++j) {
    float v = s[j];
#pragma unroll
    for (int off = 32; off >= 1; off >>= 1) v += __shfl_down(v, off, 64);
    if (lane == 0) red[wid][j] = v;
  }
  __syncthreads();
  if (t < 4) rowsum[t * BATCH + b] = red[0][t] + red[1][t] + red[2][t] + red[3][t];
}

// Split-K quantized GEMM. Block: 128(m) x 128(n) x KSLICE(k), 4 waves 2x2,
// each wave a 64x64 output tile (acc[4][4], ~120 unified regs -> 4 blocks/CU
// with 32KB LDS; grid 1024 = 4/CU for TLP-based latency hiding).
// LDS: [row][chunk] of 16B chunks, chunk' = chunk ^ ((row>>1)&3) -> every
// b128 read/write spreads over all 32 banks (round-1: conflicts == 0).
// A staged by global_load_lds (linear dest + INVERSE-swizzled global source);
// B staged through regs (nibble unpack) with swizzled ds_write_b128.
__global__ __launch_bounds__(256, 2) void qgemm(const ushort* __restrict__ xb,
                                                const int* __restrict__ pw,
                                                const float* __restrict__ scale,
                                                const float* __restrict__ rowsum,
                                                float* __restrict__ out) {
  __shared__ uint32_t As[2 * BM * 16];  // 16 KB
  __shared__ uint32_t Bs[2 * BN * 16];  // 16 KB

  const int tid = threadIdx.x;
  const int lane = tid & 63;
  const int w = tid >> 6;
  const int wm = w & 1, wn = w >> 1;
  const int lr = lane & 15, lq = lane >> 4;

  const int n0 = blockIdx.x * BN;
  const int m0 = blockIdx.y * BM;
  const int ks = blockIdx.z;

  // ---- A staging via global_load_lds ----
  // wave w instr j writes LDS linearly: row w*32+j*16+(l>>2), slot l&3.
  // Slot p of row r must hold chunk q = p ^ ((r>>1)&3); row bases are
  // multiples of 16 so the key folds to (l>>3)&3 in the global address.
  const int qsw = (lane & 3) ^ ((lane >> 3) & 3);
  const char* aG = (const char*)xb
      + (size_t)(m0 + w * 32 + (lane >> 2)) * (IN_F * 2)
      + (size_t)ks * (KSLICE * 2) + qsw * 16;
  uint32_t* aL = As + (w * 32) * 16;  // wave-uniform; +256 words = +16 rows

  // ---- B staging: thread t stages row n0+(t>>1), 32B half (t&1) ----
  const int br = tid >> 1, bh = tid & 1;
  const char* bG = (const char*)pw + (size_t)(n0 + br) * (IN_F * 2)
      + (size_t)ks * (KSLICE * 2) + bh * 32;
  uint32_t* bW = Bs + br * 16;
  const int bkey = (tid >> 2) & 3;  // (br>>1)&3
  const int c0 = bh * 2, c1 = bh * 2 + 1;

  // ---- swizzled fragment read pointers ----
  const int rkey = (lr >> 1) & 3;
  const uint32_t* aR = As + (wm * 64 + lr) * 16 + (lq ^ rkey) * 4;
  const uint32_t* bR = Bs + (wn * 64 + lr) * 16 + (lq ^ rkey) * 4;

  floatx4 acc[4][4] = {};

  // prologue: A tile 0 -> LDS buf0 (async), B tile 0 -> regs
  gl16(aG, aL);
  gl16(aG + (size_t)16 * (IN_F * 2), aL + 256);
  int4 pb0 = *(const int4*)bG;
  int4 pb1 = *(const int4*)(bG + 16);

  for (int it = 0; it < NIT; ++it) {
    const int off = (it & 1) * (BM * 16);
    // unpack + swizzled-write B tile(it)
    int4 u0, u1;
    u0.x = dq(pb0.x); u0.y = dq(pb0.y); u0.z = dq(pb0.z); u0.w = dq(pb0.w);
    u1.x = dq(pb1.x); u1.y = dq(pb1.y); u1.z = dq(pb1.z); u1.w = dq(pb1.w);
    *(int4*)(bW + off + ((c0 ^ bkey) << 2)) = u0;
    *(int4*)(bW + off + ((c1 ^ bkey) << 2)) = u1;
    __syncthreads();  // drains A gl16(it) + B ds_writes; all waves done with buf(it^1)
    // prefetch tile(it+1): A async into other LDS buf, B into regs;
    // a full compute phase to land before they're needed.
    if (it + 1 < NIT) {
      const int off2 = ((it + 1) & 1) * (BM * 16);
      const char* aN = aG + (size_t)(it + 1) * 64;
      gl16(aN, aL + off2);
      gl16(aN + (size_t)16 * (IN_F * 2), aL + off2 + 256);
      const char* bN = bG + (size_t)(it + 1) * 64;
      pb0 = *(const int4*)bN;
      pb1 = *(const int4*)(bN + 16);
    }
    // compute tile(it)
    bf16x8 av[4], bv[4];
#pragma unroll
    for (int i = 0; i < 4; ++i) av[i] = *(const bf16x8*)(aR + off + i * 256);
#pragma unroll
    for (int i = 0; i < 4; ++i) bv[i] = *(const bf16x8*)(bR + off + i * 256);
#pragma unroll
    for (int mi = 0; mi < 4; ++mi)
#pragma unroll
      for (int ni = 0; ni < 4; ++ni)
        acc[mi][ni] = __builtin_amdgcn_mfma_f32_16x16x32_bf16(av[mi], bv[ni],
                                                              acc[mi][ni], 0, 0, 0);
  }

  // epilogue: C/D layout col=lane&15, row=(lane>>4)*4+reg
  const int om = m0 + wm * 64 + lq * 4;
  const int on = n0 + wn * 64 + lr;
  float scv[4];
#pragma unroll
  for (int ni = 0; ni < 4; ++ni) scv[ni] = scale[on + ni * 16];
  float rsv[4][4];
#pragma unroll
  for (int mi = 0; mi < 4; ++mi)
#pragma unroll
    for (int rr = 0; rr < 4; ++rr)
      rsv[mi][rr] = rowsum[ks * BATCH + om + mi * 16 + rr];

#pragma unroll
  for (int mi = 0; mi < 4; ++mi)
#pragma unroll
    for (int ni = 0; ni < 4; ++ni) {
      const float s = scv[ni];
      float* op = out + (size_t)(om + mi * 16) * OUT_F + (on + ni * 16);
#pragma unroll
      for (int rr = 0; rr < 4; ++rr)
        atomicAdd(op + (size_t)rr * OUT_F, s * (acc[mi][ni][rr] - 136.f * rsv[mi][rr]));
    }
}

extern "C" void kernel_launch(void* const* d_in, const int* in_sizes, int n_in,
                              void* d_out, int out_size, void* d_ws, size_t ws_size,
                              hipStream_t stream) {
  const float* x = (const float*)d_in[0];
  const int* pw = (const int*)d_in[1];
  const float* scale = (const float*)d_in[2];
  float* out = (float*)d_out;

  ushort* xb = (ushort*)d_ws;  // 8 MiB
  float* rowsum = (float*)((char*)d_ws + (size_t)BATCH * IN_F * sizeof(ushort));  // 4x512 f32

  cvt_rowsum<<<BATCH, 256, 0, stream>>>(x, xb, rowsum, out);
  dim3 grid(OUT_F / BN, BATCH / BM, KSPLIT);
  qgemm<<<grid, 256, 0, stream>>>(xb, pw, scale, rowsum, out);
}

// Round 3
// 302.429 us; speedup vs baseline: 1.1236x; 1.0197x over previous
//
#include <hip/hip_runtime.h>
#include <cstdint>
#include <cstddef>

#define IN_F 8192
#define OUT_F 8192
#define BATCH 512
#define KSPLIT 4
#define KSLICE (IN_F / KSPLIT) /* 2048 */
#define BK 64
#define TILES (KSLICE / BK) /* 32 */
#define BM 256
#define BN 256

typedef __bf16 bf16x8 __attribute__((ext_vector_type(8)));
typedef float floatx4 __attribute__((ext_vector_type(4)));

// fp32 -> bf16 round-to-nearest-even
__device__ __forceinline__ ushort f2bf(float f) {
  uint32_t u = __float_as_uint(f);
  u += 0x7FFFu + ((u >> 16) & 1u);
  return (ushort)(u >> 16);
}

// low byte (2 nibbles) of a packed int -> bf16x2 of biased weights (q+136):
// low half = 0x4300|hi_nib (even k), high half = 0x4300|lo_nib (odd k)
__device__ __forceinline__ uint32_t dq(int p) {
  uint32_t u = (uint32_t)p;
  return (((u >> 4) & 0xFu) | ((u & 0xFu) << 16)) | 0x43004300u;
}

// async global->LDS, 16B/lane, LDS dest = wave-uniform base + lane*16
__device__ __forceinline__ void gl16(const void* g, uint32_t* l) {
  __builtin_amdgcn_global_load_lds(
      (const __attribute__((address_space(1))) uint32_t*)g,
      (__attribute__((address_space(3))) uint32_t*)l, 16, 0, 0);
}

// Pass 1: x fp32 -> bf16, per-slice rowsums of converted values, zero out.
__global__ __launch_bounds__(256) void cvt_rowsum(const float* __restrict__ x,
                                                  ushort* __restrict__ xb,
                                                  float* __restrict__ rowsum,
                                                  float* __restrict__ out) {
  const int b = blockIdx.x;
  const int t = threadIdx.x;
  const float4* xr = (const float4*)(x + (size_t)b * IN_F);
  ushort4* xo = (ushort4*)(xb + (size_t)b * IN_F);
  float4 z = {0.f, 0.f, 0.f, 0.f};
  float4* orow = (float4*)(out + (size_t)b * OUT_F);
  float s[4] = {0.f, 0.f, 0.f, 0.f};
#pragma unroll
  for (int i = 0; i < 8; ++i) {
    float4 v = xr[i * 256 + t];
    ushort4 o;
    o.x = f2bf(v.x); o.y = f2bf(v.y); o.z = f2bf(v.z); o.w = f2bf(v.w);
    xo[i * 256 + t] = o;
    orow[i * 256 + t] = z;
    s[i >> 1] += __uint_as_float((uint32_t)o.x << 16) + __uint_as_float((uint32_t)o.y << 16)
               + __uint_as_float((uint32_t)o.z << 16) + __uint_as_float((uint32_t)o.w << 16);
  }
  __shared__ float red[4][4];
  const int lane = t & 63, wid = t >> 6;
#pragma unroll
  for (int j = 0; j < 4; ++j) {
    float v = s[j];
#pragma unroll
    for (int off = 32; off >= 1; off >>= 1) v += __shfl_down(v, off, 64);
    if (lane == 0) red[wid][j] = v;
  }
  __syncthreads();
  if (t < 4) rowsum[t * BATCH + b] = red[0][t] + red[1][t] + red[2][t] + red[3][t];
}

// Split-K quantized GEMM, 256x256x(BK=64) tile, 512 thr, 8 waves (2m x 4n),
// per-wave 128x64 out (acc[8][4]). Counted-vmcnt deep pipeline: next tile's
// A gloads + B packed loads stay in flight across BOTH raw s_barriers
// (vmcnt(8) retires only the 4 oldest = current tile's A gloads).
// LDS rows = 64 bf16 = 8 chunks of 16B; slot = chunk ^ (row&7) swizzle on
// A-gload source / B ds_write / all fragment reads.
__global__ __launch_bounds__(512, 2) void qgemm(const ushort* __restrict__ xb,
                                                const int* __restrict__ pw,
                                                const float* __restrict__ scale,
                                                const float* __restrict__ rowsum,
                                                float* __restrict__ out) {
  __shared__ uint32_t As[2 * BM * 32];  // 64 KB
  __shared__ uint32_t Bs[2 * BN * 32];  // 64 KB

  const int tid = threadIdx.x;
  const int lane = tid & 63;
  const int w = tid >> 6;
  const int wm = w >> 2, wn = w & 3;
  const int lr = lane & 15, lq = lane >> 4;

  const int n0 = blockIdx.x * BN;
  const int m0 = blockIdx.y * BM;
  const int ks = blockIdx.z;

  // A gload: wave w instr j covers rows w*32+j*8..+8, slot l&7 linear.
  // Slot p of row r holds chunk p ^ (r&7); r&7 == (l>>3)&7 -> fold into src.
  const char* aSrc = (const char*)xb
      + (size_t)(m0 + w * 32 + (lane >> 3)) * (IN_F * 2)
      + (size_t)ks * (KSLICE * 2)
      + (size_t)((((lane & 7) ^ ((lane >> 3) & 7)) * 16));
  uint32_t* aDst = As + (w * 32) * 32;  // + j*256 + buf*8192

  // B packed: thread t owns row rt = t>>1, chunks {c0,c0+1,c0+4,c0+5}
  const int rt = tid >> 1;
  const int c0 = (tid & 1) * 2;
  const int rk = rt & 7;
  const int* bSrc = pw + (size_t)(n0 + rt) * (IN_F / 2) + ks * (KSLICE / 2);

  // fragment read word-offsets (slot = (kh*4+lq) ^ (lr&7); kh applied as ^16)
  const int key = lr & 7;
  const int aOff = (wm * 128 + lr) * 32 + ((lq ^ key) * 4);
  const int bOff = (wn * 64 + lr) * 32 + ((lq ^ key) * 4);

  floatx4 acc[8][4] = {};

  auto stB = [&](int nb, int q, int4 p) {
    int4 u;
    u.x = dq(p.x); u.y = dq(p.y); u.z = dq(p.z); u.w = dq(p.w);
    *(int4*)(Bs + nb * 8192 + rt * 32 + ((q ^ rk) * 4)) = u;
  };

#define RD_BV(kh)                                                            \
  _Pragma("unroll") for (int fn = 0; fn < 4; ++fn)                           \
      bv[fn] = *(const bf16x8*)(Bs + (((bOff + fn * 512) ^ ((kh)*16)) + buf * 8192));
#define RD_AV(mh, kh)                                                        \
  _Pragma("unroll") for (int fm = 0; fm < 4; ++fm)                           \
      av[fm] = *(const bf16x8*)(As + (((aOff + (mh)*2048 + fm * 512) ^ ((kh)*16)) + buf * 8192));
#define MFMA_BLK(mh)                                                         \
  __builtin_amdgcn_s_setprio(1);                                             \
  _Pragma("unroll") for (int fm = 0; fm < 4; ++fm)                           \
      _Pragma("unroll") for (int fn = 0; fn < 4; ++fn)                       \
          acc[(mh)*4 + fm][fn] = __builtin_amdgcn_mfma_f32_16x16x32_bf16(    \
              av[fm], bv[fn], acc[(mh)*4 + fm][fn], 0, 0, 0);                \
  __builtin_amdgcn_s_setprio(0);

  // ---- prologue: stage tile 0 into buf 0 ----
  {
    int4 p0 = *(const int4*)(bSrc + c0 * 4);
    int4 p1 = *(const int4*)(bSrc + c0 * 4 + 4);
    int4 p2 = *(const int4*)(bSrc + (c0 + 4) * 4);
    int4 p3 = *(const int4*)(bSrc + (c0 + 4) * 4 + 4);
    stB(0, c0, p0); stB(0, c0 + 1, p1); stB(0, c0 + 4, p2); stB(0, c0 + 5, p3);
    gl16(aSrc, aDst);
    gl16(aSrc + 131072, aDst + 256);
    gl16(aSrc + 262144, aDst + 512);
    gl16(aSrc + 393216, aDst + 768);
    asm volatile("s_waitcnt lgkmcnt(0)" ::: "memory");
  }

  for (int t = 0; t < TILES - 1; ++t) {
    const int buf = t & 1, nb = buf ^ 1;
    // issue staging for tile t+1 (pinned between barrier-asm fences)
    const int* bs = bSrc + (t + 1) * 32;
    int4 pb0 = *(const int4*)(bs + c0 * 4);
    int4 pb1 = *(const int4*)(bs + c0 * 4 + 4);
    int4 pb2 = *(const int4*)(bs + (c0 + 4) * 4);
    int4 pb3 = *(const int4*)(bs + (c0 + 4) * 4 + 4);
    const char* as = aSrc + (size_t)(t + 1) * 128;
    gl16(as, aDst + nb * 8192);
    gl16(as + 131072, aDst + nb * 8192 + 256);
    gl16(as + 262144, aDst + nb * 8192 + 512);
    gl16(as + 393216, aDst + nb * 8192 + 768);
    // retire ONLY tile t's 4 A-gloads (oldest); t+1's 8 ops stay in flight
    asm volatile("s_waitcnt vmcnt(8)" ::: "memory");
    asm volatile("s_barrier" ::: "memory");  // publish tile t staging

    bf16x8 av[4], bv[4];
    RD_BV(0);
    RD_AV(0, 0); MFMA_BLK(0);
    stB(nb, c0, pb0); stB(nb, c0 + 1, pb1);
    RD_AV(1, 0); MFMA_BLK(1);
    RD_BV(1);
    RD_AV(0, 1); MFMA_BLK(0);
    stB(nb, c0 + 4, pb2); stB(nb, c0 + 5, pb3);
    RD_AV(1, 1); MFMA_BLK(1);

    asm volatile("s_waitcnt lgkmcnt(0)" ::: "memory");  // drain own B writes
    asm volatile("s_barrier" ::: "memory");             // tile boundary
  }

  // ---- tail tile (no staging) ----
  {
    const int buf = (TILES - 1) & 1;
    asm volatile("s_waitcnt vmcnt(0)" ::: "memory");
    asm volatile("s_barrier" ::: "memory");
    bf16x8 av[4], bv[4];
    RD_BV(0);
    RD_AV(0, 0); MFMA_BLK(0);
    RD_AV(1, 0); MFMA_BLK(1);
    RD_BV(1);
    RD_AV(0, 1); MFMA_BLK(0);
    RD_AV(1, 1); MFMA_BLK(1);
  }

  // epilogue: C/D layout col=lane&15, row=(lane>>4)*4+reg
  const int omb = m0 + wm * 128 + lq * 4;
  const int on = n0 + wn * 64 + lr;
  float scv[4];
#pragma unroll
  for (int fn = 0; fn < 4; ++fn) scv[fn] = scale[on + fn * 16];
  float rsv[8][4];
#pragma unroll
  for (int fmg = 0; fmg < 8; ++fmg)
#pragma unroll
    for (int rr = 0; rr < 4; ++rr)
      rsv[fmg][rr] = rowsum[ks * BATCH + omb + fmg * 16 + rr];

#pragma unroll
  for (int fmg = 0; fmg < 8; ++fmg)
#pragma unroll
    for (int fn = 0; fn < 4; ++fn) {
      const float s = scv[fn];
      float* op = out + (size_t)(omb + fmg * 16) * OUT_F + (on + fn * 16);
#pragma unroll
      for (int rr = 0; rr < 4; ++rr)
        atomicAdd(op + (size_t)rr * OUT_F, s * (acc[fmg][fn][rr] - 136.f * rsv[fmg][rr]));
    }
#undef RD_BV
#undef RD_AV
#undef MFMA_BLK
}

extern "C" void kernel_launch(void* const* d_in, const int* in_sizes, int n_in,
                              void* d_out, int out_size, void* d_ws, size_t ws_size,
                              hipStream_t stream) {
  const float* x = (const float*)d_in[0];
  const int* pw = (const int*)d_in[1];
  const float* scale = (const float*)d_in[2];
  float* out = (float*)d_out;

  ushort* xb = (ushort*)d_ws;  // 8 MiB
  float* rowsum = (float*)((char*)d_ws + (size_t)BATCH * IN_F * sizeof(ushort));  // 4x512 f32

  cvt_rowsum<<<BATCH, 256, 0, stream>>>(x, xb, rowsum, out);
  dim3 grid(OUT_F / BN, BATCH / BM, KSPLIT);
  qgemm<<<grid, 512, 0, stream>>>(xb, pw, scale, rowsum, out);
}